// Round 2
// 359.939 us; speedup vs baseline: 1.0074x; 1.0074x over previous
//
#include <hip/hip_runtime.h>
#include <hip/hip_bf16.h>
#include <math.h>

typedef unsigned short ushort_t;
typedef unsigned int u32;

constexpr int D  = 512;
constexpr int T  = 8192;
constexpr int B  = 8;
constexpr int H  = 8;
constexpr int KS = 64;
constexpr int HD = 64;
constexpr float SCALE = 0.125f;
constexpr float LNEPS = 1e-5f;
constexpr float EPS   = 1e-20f;

constexpr int TC  = 128;   // tokens per chunk
constexpr int CPB = 2;     // chunks per block

// ws layout (float units)
constexpr size_t OFF_S    = 0;         // 64*512
constexpr size_t OFF_BQ   = 32768;     // 512
constexpr size_t OFF_SACC = 33280;     // 8*8*64*64 = 262144
constexpr size_t OFF_CACC = 295424;    // 8*8*64 = 4096
constexpr size_t OFF_WB2  = 299520;    // bf16[1024*512] (1 MB) lives here

typedef __attribute__((ext_vector_type(8))) short bf16x8;
typedef __attribute__((ext_vector_type(4))) float f32x4;
typedef __attribute__((ext_vector_type(4))) unsigned short us4;

typedef const __attribute__((address_space(1))) u32* gas_ptr;
typedef __attribute__((address_space(3))) u32* las_ptr;

__device__ __forceinline__ void gload16(const void* g, void* l) {
  __builtin_amdgcn_global_load_lds((gas_ptr)g, (las_ptr)l, 16, 0, 0);
}

__device__ __forceinline__ ushort_t f2bf(float x) {
  __hip_bfloat16 t = __float2bfloat16(x);
  return *(ushort_t*)&t;
}

__device__ __forceinline__ u32 pk2bf(float x, float y) {
  __hip_bfloat162 t = __float22bfloat162_rn(make_float2(x, y));
  return *(u32*)&t;
}

__device__ __forceinline__ bf16x8 cvt8(f32x4 a, f32x4 b) {
  union { bf16x8 v; u32 u[4]; } r;
  r.u[0] = pk2bf(a.x, a.y); r.u[1] = pk2bf(a.z, a.w);
  r.u[2] = pk2bf(b.x, b.y); r.u[3] = pk2bf(b.z, b.w);
  return r.v;
}

// ---------- setup: layernorm of slots ----------
__global__ void ln_slots_kernel(const float* __restrict__ slots_w,
                                const float* __restrict__ g, const float* __restrict__ b,
                                float* __restrict__ S) {
  __shared__ float red[8];
  int k = blockIdx.x;
  int tid = threadIdx.x;
  float x0 = slots_w[k*D + tid];
  float x1 = slots_w[k*D + tid + 256];
  float s1 = x0 + x1, s2 = x0*x0 + x1*x1;
  for (int off = 32; off; off >>= 1) { s1 += __shfl_xor(s1, off); s2 += __shfl_xor(s2, off); }
  if ((tid & 63) == 0) { red[tid >> 6] = s1; red[4 + (tid >> 6)] = s2; }
  __syncthreads();
  s1 = red[0] + red[1] + red[2] + red[3];
  s2 = red[4] + red[5] + red[6] + red[7];
  float mu = s1 / D;
  float var = s2 / D - mu * mu;
  float rs = rsqrtf(var + LNEPS);
  S[k*D + tid]       = (x0 - mu) * rs * g[tid]       + b[tid];
  S[k*D + tid + 256] = (x1 - mu) * rs * g[tid + 256] + b[tid + 256];
}

// ---------- setup: Wb2[(h*128+k)][in] = bf16(scale * sum_d S[k][h*64+d] * Wk[h*64+d][in]) ----------
__global__ void weff_kernel(const float* __restrict__ S, const float* __restrict__ Wk,
                            ushort_t* __restrict__ Wb2) {
  int gid = blockIdx.x * 256 + threadIdx.x;   // 0..262143
  int in = gid & 511;
  int hk = gid >> 9;          // uniform per block
  int h = hk >> 6, k = hk & 63;
  const float* srow = S + k*D + h*HD;
  const float* wcol = Wk + (size_t)(h*HD)*D + in;
  float acc = 0.f;
  #pragma unroll 8
  for (int d = 0; d < HD; ++d) acc += srow[d] * wcol[(size_t)d*D];
  Wb2[(size_t)(h*128 + k)*D + in] = f2bf(acc * SCALE);
}

// ---------- setup: bq[hk] = scale * sum_d S[k][h*64+d] * bk[h*64+d] ----------
__global__ void bq_kernel(const float* __restrict__ S, const float* __restrict__ bk,
                          float* __restrict__ bq) {
  int hk = blockIdx.x * 256 + threadIdx.x;
  int h = hk >> 6, k = hk & 63;
  float acc = 0.f;
  for (int d = 0; d < HD; ++d) acc += S[k*D + h*HD + d] * bk[h*HD + d];
  bq[hk] = acc * SCALE;
}

// ---------- setup: Wb2[(h*128+64+d)][in] = bf16(Wv[h*64+d][in]) ----------
__global__ void wvcopy_kernel(const float* __restrict__ Wv, ushort_t* __restrict__ Wb2) {
  int gid = blockIdx.x * 256 + threadIdx.x;   // 0..262143
  int in = gid & 511;
  int hd = gid >> 9;
  int h = hd >> 6, d = hd & 63;
  Wb2[(size_t)(h*128 + 64 + d)*D + in] = f2bf(Wv[(size_t)hd*D + in]);
}

__global__ void zero_kernel(float* __restrict__ p, int n) {
  int gid = blockIdx.x * 256 + threadIdx.x;
  if (gid < n) p[gid] = 0.f;
}

// ---------- main fused MFMA kernel ----------
// grid = 2048 blocks, 256 threads (4 waves, 2x2 wave grid).
// K-loop: double-buffered global_load_lds prefetch with counted vmcnt (T3/T4),
// XOR-swizzled LDS (pre-swizzled global source + swizzled ds_read) to kill
// the 16-way (A, 128B rows) and 8-way (B, 64B rows) bank conflicts (T2, rule 21).
__global__ __launch_bounds__(256, 3) void main_kernel(
    const float* __restrict__ X, const ushort_t* __restrict__ Wb2,
    const float* __restrict__ bq, const float* __restrict__ bv,
    float* __restrict__ Sacc, float* __restrict__ Cacc) {
  __shared__ __align__(16) char smem[49152];
  float*    A0 = (float*)smem;                        // [128][32] fp32, 16 KB
  float*    A1 = (float*)(smem + 16384);              // 16 KB
  ushort_t* B0 = (ushort_t*)(smem + 32768);           // [128][32] bf16, 8 KB
  ushort_t* B1 = (ushort_t*)(smem + 40960);           // 8 KB
  ushort_t* W_lds = (ushort_t*)smem;                  // [64 slots][136 tokens] bf16 (overlay)
  ushort_t* V_lds = (ushort_t*)(smem + 17408);        // [64 dims ][136 tokens] bf16 (overlay)

  const int tid  = threadIdx.x;
  const int lane = tid & 63, w = tid >> 6;
  const int wm = w & 1, wn = w >> 1;
  const int m16 = lane & 15, q = lane >> 4;

  const int id = blockIdx.x;
  const int h  = (id >> 3) & 7;
  const int cg = (id & 7) | ((id >> 6) << 3);         // 0..255
  const int bh = (cg >> 5) * H + h;                    // batch*H + head

  const ushort_t* Wp = Wb2 + (size_t)h * 128 * D;

  f32x4 acc2[4] = {};                                  // phase-2 accum (16 slots x 64 dims per wave)
  float csum[4] = {0.f, 0.f, 0.f, 0.f};

  for (int cc = 0; cc < CPB; ++cc) {
    const float* Xc = X + (size_t)(cg * CPB + cc) * TC * D;
    f32x4 acc[4][4] = {};                              // phase-1 accum 64x64 per wave

    // ---- prologue: stage K-step 0 into buffer 0 (6 gload_lds / thread) ----
    #pragma unroll
    for (int m = 0; m < 4; ++m) {
      int li = tid + m * 256;                          // 0..1023
      int row = li >> 3, c = li & 7;
      gload16(Xc + (size_t)row * D + ((c ^ (row & 7)) * 4), A0 + (size_t)li * 4);
    }
    #pragma unroll
    for (int m = 0; m < 2; ++m) {
      int li = tid + m * 256;                          // 0..511
      int col = li >> 2, c = li & 3;
      gload16(Wp + (size_t)col * D + ((c ^ ((col >> 1) & 3)) * 8), B0 + (size_t)li * 8);
    }

    #pragma unroll 2
    for (int t = 0; t < 16; ++t) {
      const float*    Ab = (t & 1) ? A1 : A0;
      const ushort_t* Bb = (t & 1) ? B1 : B0;
      if (t < 15) {
        // ---- prefetch K-step t+1 into the other buffer BEFORE computing t ----
        float*    An = (t & 1) ? A0 : A1;
        ushort_t* Bn = (t & 1) ? B0 : B1;
        int kb = (t + 1) * 32;
        #pragma unroll
        for (int m = 0; m < 4; ++m) {
          int li = tid + m * 256;
          int row = li >> 3, c = li & 7;
          gload16(Xc + (size_t)row * D + kb + ((c ^ (row & 7)) * 4), An + (size_t)li * 4);
        }
        #pragma unroll
        for (int m = 0; m < 2; ++m) {
          int li = tid + m * 256;
          int col = li >> 2, c = li & 3;
          gload16(Wp + (size_t)col * D + kb + ((c ^ ((col >> 1) & 3)) * 8), Bn + (size_t)li * 8);
        }
        // wait only for step t's 6 loads; step t+1's 6 stay in flight
        asm volatile("s_waitcnt vmcnt(6)" ::: "memory");
      } else {
        asm volatile("s_waitcnt vmcnt(0)" ::: "memory");
      }
      __builtin_amdgcn_s_barrier();
      __builtin_amdgcn_sched_barrier(0);

      // ---- compute step t from current buffer (swizzled reads) ----
      bf16x8 af[4], bfr[4];
      #pragma unroll
      for (int i = 0; i < 4; ++i) {
        int r = wm * 64 + i * 16 + m16;
        int sw = r & 7;
        f32x4 a0 = *(const f32x4*)(Ab + (size_t)r * 32 + (((2 * q)     ^ sw) * 4));
        f32x4 a1 = *(const f32x4*)(Ab + (size_t)r * 32 + (((2 * q + 1) ^ sw) * 4));
        af[i] = cvt8(a0, a1);
      }
      #pragma unroll
      for (int j = 0; j < 4; ++j) {
        int cl = wn * 64 + j * 16 + m16;
        bfr[j] = *(const bf16x8*)(Bb + (size_t)cl * 32 + ((q ^ ((cl >> 1) & 3)) * 8));
      }
      #pragma unroll
      for (int i = 0; i < 4; ++i)
        #pragma unroll
        for (int j = 0; j < 4; ++j)
          acc[i][j] = __builtin_amdgcn_mfma_f32_16x16x32_bf16(af[i], bfr[j], acc[i][j], 0, 0, 0);

      if (t < 15) {
        // protect current buffer before next iteration overwrites it
        __builtin_amdgcn_sched_barrier(0);
        __builtin_amdgcn_s_barrier();
      }
    }
    __syncthreads();   // phase-1 LDS reads done; safe to overwrite with W/V

    if (wn == 0) {
      // these waves hold logits: cols (lane&15)+j*16 = slots, rows = tokens
      float bqv[4];
      #pragma unroll
      for (int j = 0; j < 4; ++j) bqv[j] = bq[h * KS + j * 16 + m16];
      #pragma unroll
      for (int i = 0; i < 4; ++i) {
        us4 wp[4];
        #pragma unroll
        for (int r = 0; r < 4; ++r) {
          float v0 = acc[i][0][r] + bqv[0];
          float v1 = acc[i][1][r] + bqv[1];
          float v2 = acc[i][2][r] + bqv[2];
          float v3 = acc[i][3][r] + bqv[3];
          float mx = fmaxf(fmaxf(v0, v1), fmaxf(v2, v3));
          mx = fmaxf(mx, __shfl_xor(mx, 1));
          mx = fmaxf(mx, __shfl_xor(mx, 2));
          mx = fmaxf(mx, __shfl_xor(mx, 4));
          mx = fmaxf(mx, __shfl_xor(mx, 8));
          v0 = __expf(v0 - mx); v1 = __expf(v1 - mx);
          v2 = __expf(v2 - mx); v3 = __expf(v3 - mx);
          float s = v0 + v1 + v2 + v3;
          s += __shfl_xor(s, 1); s += __shfl_xor(s, 2);
          s += __shfl_xor(s, 4); s += __shfl_xor(s, 8);
          float inv = __builtin_amdgcn_rcpf(s);
          v0 *= inv; v1 *= inv; v2 *= inv; v3 *= inv;
          csum[0] += v0; csum[1] += v1; csum[2] += v2; csum[3] += v3;
          wp[0][r] = f2bf(v0); wp[1][r] = f2bf(v1);
          wp[2][r] = f2bf(v2); wp[3][r] = f2bf(v3);
        }
        #pragma unroll
        for (int j = 0; j < 4; ++j)
          *(us4*)(W_lds + (j * 16 + m16) * 136 + wm * 64 + i * 16 + q * 4) = wp[j];
      }
    } else {
      // these waves hold V: cols = head dims
      float bvv[4];
      #pragma unroll
      for (int j = 0; j < 4; ++j) bvv[j] = bv[h * HD + j * 16 + m16];
      #pragma unroll
      for (int i = 0; i < 4; ++i) {
        #pragma unroll
        for (int j = 0; j < 4; ++j) {
          us4 pk;
          pk.x = f2bf(acc[i][j][0] + bvv[j]);
          pk.y = f2bf(acc[i][j][1] + bvv[j]);
          pk.z = f2bf(acc[i][j][2] + bvv[j]);
          pk.w = f2bf(acc[i][j][3] + bvv[j]);
          *(us4*)(V_lds + (j * 16 + m16) * 136 + wm * 64 + i * 16 + q * 4) = pk;
        }
      }
    }
    __syncthreads();

    // phase 2: S_part[slot][d] += sum_tokens W[slot][t] * V[d][t]; each wave: 16 slots x 64 d
    #pragma unroll
    for (int kk = 0; kk < 4; ++kk) {
      bf16x8 a = *(const bf16x8*)(W_lds + (w * 16 + m16) * 136 + kk * 32 + q * 8);
      #pragma unroll
      for (int j = 0; j < 4; ++j) {
        bf16x8 bb = *(const bf16x8*)(V_lds + (j * 16 + m16) * 136 + kk * 32 + q * 8);
        acc2[j] = __builtin_amdgcn_mfma_f32_16x16x32_bf16(a, bb, acc2[j], 0, 0, 0);
      }
    }
    __syncthreads();   // phase-2 reads done before next chunk's staging overwrites W/V region
  }

  // flush accumulators (one atomic pass for both chunks)
  float* Sb = Sacc + (size_t)bh * KS * HD;
  #pragma unroll
  for (int j = 0; j < 4; ++j)
    #pragma unroll
    for (int r = 0; r < 4; ++r)
      atomicAdd(Sb + (w * 16 + q * 4 + r) * HD + j * 16 + m16, acc2[j][r]);

  if (wn == 0) {
    #pragma unroll
    for (int j = 0; j < 4; ++j) {
      float c = csum[j];
      c += __shfl_xor(c, 16);
      c += __shfl_xor(c, 32);
      if (q == 0) atomicAdd(Cacc + (size_t)bh * KS + j * 16 + m16, c);
    }
  }
}

// ---------- finalize: divide by (C+eps), layernorm, write out ----------
__global__ void finalize_kernel(const float* __restrict__ Sacc, const float* __restrict__ Cacc,
                                const float* __restrict__ g, const float* __restrict__ bb,
                                float* __restrict__ out) {
  __shared__ float red[8];
  int bk_ = blockIdx.x;           // b*64 + k
  int b = bk_ >> 6, k = bk_ & 63;
  int tid = threadIdx.x;
  float v[2];
  #pragma unroll
  for (int m = 0; m < 2; ++m) {
    int d = tid + m*256;
    int h = d >> 6, dd = d & 63;
    float c = Cacc[((size_t)b*H + h)*KS + k];
    v[m] = Sacc[(((size_t)b*H + h)*KS + k)*HD + dd] / (c + EPS);
  }
  float s1 = v[0] + v[1], s2 = v[0]*v[0] + v[1]*v[1];
  for (int off = 32; off; off >>= 1) { s1 += __shfl_xor(s1, off); s2 += __shfl_xor(s2, off); }
  if ((tid & 63) == 0) { red[tid >> 6] = s1; red[4 + (tid >> 6)] = s2; }
  __syncthreads();
  s1 = red[0] + red[1] + red[2] + red[3];
  s2 = red[4] + red[5] + red[6] + red[7];
  float mu = s1 / D;
  float var = s2 / D - mu * mu;
  float rs = rsqrtf(var + LNEPS);
  #pragma unroll
  for (int m = 0; m < 2; ++m) {
    int d = tid + m*256;
    out[(size_t)bk_*D + d] = (v[m] - mu) * rs * g[d] + bb[d];
  }
}

extern "C" void kernel_launch(void* const* d_in, const int* in_sizes, int n_in,
                              void* d_out, int out_size, void* d_ws, size_t ws_size,
                              hipStream_t stream) {
  const float* X       = (const float*)d_in[0];
  const float* slots_w = (const float*)d_in[1];
  const float* g_slots = (const float*)d_in[2];
  const float* b_slots = (const float*)d_in[3];
  const float* Wk      = (const float*)d_in[4];
  const float* bk      = (const float*)d_in[5];
  const float* Wv      = (const float*)d_in[6];
  const float* bv      = (const float*)d_in[7];
  const float* g_after = (const float*)d_in[8];
  const float* b_after = (const float*)d_in[9];
  float* ws   = (float*)d_ws;
  float* S    = ws + OFF_S;
  float* bq   = ws + OFF_BQ;
  float* Sacc = ws + OFF_SACC;
  float* Cacc = ws + OFF_CACC;
  ushort_t* Wb2 = (ushort_t*)(ws + OFF_WB2);
  float* out  = (float*)d_out;

  hipLaunchKernelGGL(ln_slots_kernel, dim3(64), dim3(256), 0, stream, slots_w, g_slots, b_slots, S);
  hipLaunchKernelGGL(weff_kernel, dim3(1024), dim3(256), 0, stream, S, Wk, Wb2);
  hipLaunchKernelGGL(bq_kernel, dim3(2), dim3(256), 0, stream, S, bk, bq);
  hipLaunchKernelGGL(wvcopy_kernel, dim3(1024), dim3(256), 0, stream, Wv, Wb2);
  hipLaunchKernelGGL(zero_kernel, dim3(1040), dim3(256), 0, stream, Sacc, 266240);
  hipLaunchKernelGGL(main_kernel, dim3(2048), dim3(256), 0, stream, X, Wb2, bq, bv, Sacc, Cacc);
  hipLaunchKernelGGL(finalize_kernel, dim3(B * KS), dim3(256), 0, stream,
                     Sacc, Cacc, g_after, b_after, out);
}